// Round 3
// baseline (198.119 us; speedup 1.0000x reference)
//
#include <hip/hip_runtime.h>
#include <math.h>

#define NUM_GT 6400      // B(128) * N(50)
#define NPB 50           // GTs per batch
#define BLK 1024         // 16 waves, one CU — whole problem in one workgroup
#define PER_T ((NUM_GT + BLK - 1) / BLK)     // 7 (last iteration partial)

__global__ __launch_bounds__(BLK) void yolo_one(
    const float* __restrict__ cls0, const float* __restrict__ box0,
    const float* __restrict__ cls1, const float* __restrict__ box1,
    const float* __restrict__ cls2, const float* __restrict__ box2,
    const float4* __restrict__ gt_boxes, const int* __restrict__ gt_labels,
    float* __restrict__ out)
{
    const int t = threadIdx.x;
    float box_acc = 0.f, cls_acc = 0.f;

#pragma unroll
    for (int k = 0; k < PER_T; ++k) {
        const int i = t + k * BLK;          // consecutive threads -> consecutive GTs (coalesced)
        if (i < NUM_GT) {
            const int b = i / NPB;
            const float4 g = gt_boxes[i];
            const int label = gt_labels[i];
            const float x1 = g.x * 640.f, y1 = g.y * 640.f;
            const float x2 = g.z * 640.f, y2 = g.w * 640.f;
            const float area = (x2 - x1) * (y2 - y1);   // may be negative; matches ref
            const int s = (area < 25600.f) ? 0 : ((area < 102400.f) ? 1 : 2);
            const float cx = (x1 + x2) * 0.5f, cy = (y1 + y2) * 0.5f;

            const int   G        = (s == 0) ? 80 : ((s == 1) ? 40 : 20);
            const float stride_f = (s == 0) ? 8.f : ((s == 1) ? 16.f : 32.f);
            const float inv_str  = (s == 0) ? 0.125f : ((s == 1) ? 0.0625f : 0.03125f);
            const float* __restrict__ cls_p = (s == 0) ? cls0 : ((s == 1) ? cls1 : cls2);
            const float* __restrict__ box_p = (s == 0) ? box0 : ((s == 1) ? box1 : box2);

            int gx = (int)(cx * inv_str);   // cx>=0, trunc == astype(int32); *2^-k exact
            int gy = (int)(cy * inv_str);
            gx = min(max(gx, 0), G - 1);
            gy = min(max(gy, 0), G - 1);

            const size_t cell = ((size_t)b * G + gy) * G + gx;

            // Scattered box load issued before the BCE loop so both gather rounds overlap.
            const float4 pb = ((const float4*)box_p)[cell];
            const float4* __restrict__ pc4 = (const float4*)(cls_p + cell * 20);

            // ---- BCE over 20 classes (mean) ----
            // sum_c [onehot*log(p) + (1-onehot)*log1p(-p)]
            //   = sum_c log1p(-p_c) - log1p(-p_label) + log(p_label)
            // (each term clamped at -100 before summation, matching ref)
            float sum_l1m = 0.f;
            float p_lab = 0.5f;             // always overwritten (label in [0,20))
#pragma unroll
            for (int q = 0; q < 5; ++q) {
                float4 v = pc4[q];
                float p[4] = {v.x, v.y, v.z, v.w};
#pragma unroll
                for (int kk = 0; kk < 4; ++kk) {
                    const int c = q * 4 + kk;
                    sum_l1m += fmaxf(log1pf(-p[kk]), -100.f);
                    if (c == label) p_lab = p[kk];
                }
            }
            const float lp_lab  = fmaxf(logf(p_lab),    -100.f);
            const float l1m_lab = fmaxf(log1pf(-p_lab), -100.f);
            cls_acc += -(sum_l1m - l1m_lab + lp_lab) * (1.f / 20.f);

            // ---- box decode + IoU ----
            const float px = ((float)gx + pb.x) * stride_f;
            const float py = ((float)gy + pb.y) * stride_f;
            const float pw = pb.z * 640.f, ph = pb.w * 640.f;
            const float bx1 = px - pw * 0.5f, by1 = py - ph * 0.5f;
            const float bx2 = px + pw * 0.5f, by2 = py + ph * 0.5f;

            const float ix1 = fmaxf(bx1, x1), iy1 = fmaxf(by1, y1);
            const float ix2 = fminf(bx2, x2), iy2 = fminf(by2, y2);
            const float inter = fmaxf(ix2 - ix1, 0.f) * fmaxf(iy2 - iy1, 0.f);
            const float a1 = (bx2 - bx1) * (by2 - by1);
            const float a2 = (x2 - x1) * (y2 - y1);
            const float iou = inter / (a1 + a2 - inter + 1e-6f);

            box_acc += 1.f - iou;
        }
    }

    // ---- wave (64) shuffle reduction ----
#pragma unroll
    for (int off = 32; off > 0; off >>= 1) {
        box_acc += __shfl_down(box_acc, off);
        cls_acc += __shfl_down(cls_acc, off);
    }

    // ---- cross-wave reduction (16 waves) ----
    __shared__ float sbox[BLK / 64], scls[BLK / 64];
    const int wid = t >> 6, lane = t & 63;
    if (lane == 0) { sbox[wid] = box_acc; scls[wid] = cls_acc; }
    __syncthreads();

    if (t < 64) {
        float b = (t < BLK / 64) ? sbox[t] : 0.f;
        float c = (t < BLK / 64) ? scls[t] : 0.f;
#pragma unroll
        for (int off = 8; off > 0; off >>= 1) {   // 16 values live in lanes 0..15
            b += __shfl_down(b, off);
            c += __shfl_down(c, off);
        }
        if (t == 0) {
            const float box_loss = b * (1.f / (float)NUM_GT);
            const float cls_loss = c * (1.f / (float)NUM_GT);
            out[0] = 7.5f * box_loss + 0.5f * cls_loss;
            out[1] = box_loss;
            out[2] = cls_loss;
            out[3] = 0.f;
        }
    }
}

extern "C" void kernel_launch(void* const* d_in, const int* in_sizes, int n_in,
                              void* d_out, int out_size, void* d_ws, size_t ws_size,
                              hipStream_t stream)
{
    const float*  cls0 = (const float*)d_in[0];
    const float*  box0 = (const float*)d_in[1];
    const float*  cls1 = (const float*)d_in[2];
    const float*  box1 = (const float*)d_in[3];
    const float*  cls2 = (const float*)d_in[4];
    const float*  box2 = (const float*)d_in[5];
    const float4* gtb  = (const float4*)d_in[6];
    const int*    gtl  = (const int*)d_in[7];
    float* out = (float*)d_out;

    // Single regular launch; one workgroup does gather + loss + full reduction.
    // No workspace use, no second dispatch, no cooperative overhead.
    yolo_one<<<1, BLK, 0, stream>>>(cls0, box0, cls1, box1, cls2, box2, gtb, gtl, out);
}

// Round 7
// 121.392 us; speedup vs baseline: 1.6321x; 1.6321x over previous
//
#include <hip/hip_runtime.h>
#include <math.h>

#define NUM_GT 6400      // B(128) * N(50)
#define NPB 50           // GTs per batch
#define BLK 256
#define NBLOCKS ((NUM_GT + BLK - 1) / BLK)   // 25 blocks -> 25 CUs active

// ws layout: ws[0]=box sum, ws[1]=cls sum, ws[2]=ticket (uint), ws[3]=pad
// all zeroed by hipMemsetAsync before the kernel each iteration (workspace is
// re-poisoned by the harness each iteration, so state cannot persist).

__global__ __launch_bounds__(BLK) void yolo_wide(
    const float* __restrict__ cls0, const float* __restrict__ box0,
    const float* __restrict__ cls1, const float* __restrict__ box1,
    const float* __restrict__ cls2, const float* __restrict__ box2,
    const float4* __restrict__ gt_boxes, const int* __restrict__ gt_labels,
    float* __restrict__ ws, float* __restrict__ out)
{
    const int i = blockIdx.x * BLK + threadIdx.x;   // grid exactly covers 6400
    float box_acc, cls_acc;

    {
        const int b = i / NPB;
        const float4 g = gt_boxes[i];               // coalesced
        const int label = gt_labels[i];             // coalesced
        const float x1 = g.x * 640.f, y1 = g.y * 640.f;
        const float x2 = g.z * 640.f, y2 = g.w * 640.f;
        const float area = (x2 - x1) * (y2 - y1);   // may be negative; matches ref
        const int s = (area < 25600.f) ? 0 : ((area < 102400.f) ? 1 : 2);
        const float cx = (x1 + x2) * 0.5f, cy = (y1 + y2) * 0.5f;

        const int   G        = (s == 0) ? 80 : ((s == 1) ? 40 : 20);
        const float stride_f = (s == 0) ? 8.f : ((s == 1) ? 16.f : 32.f);
        const float inv_str  = (s == 0) ? 0.125f : ((s == 1) ? 0.0625f : 0.03125f);
        const float* __restrict__ cls_p = (s == 0) ? cls0 : ((s == 1) ? cls1 : cls2);
        const float* __restrict__ box_p = (s == 0) ? box0 : ((s == 1) ? box1 : box2);

        int gx = (int)(cx * inv_str);               // cx>=0, trunc == astype(int32)
        int gy = (int)(cy * inv_str);
        gx = min(max(gx, 0), G - 1);
        gy = min(max(gy, 0), G - 1);

        const size_t cell = ((size_t)b * G + gy) * G + gx;

        // Scattered box load issued before the BCE loop so both gather rounds overlap.
        const float4 pb = ((const float4*)box_p)[cell];
        const float4* __restrict__ pc4 = (const float4*)(cls_p + cell * 20);

        // ---- BCE over 20 classes (mean) ----
        // sum_c [onehot*log(p) + (1-onehot)*log1p(-p)]
        //   = sum_c log1p(-p_c) - log1p(-p_label) + log(p_label)
        // 21 log1pf + 1 logf instead of 20 + 20 transcendentals.
        float sum_l1m = 0.f;
        float p_lab = 0.5f;                          // always overwritten (label in [0,20))
#pragma unroll
        for (int q = 0; q < 5; ++q) {
            float4 v = pc4[q];
            float p[4] = {v.x, v.y, v.z, v.w};
#pragma unroll
            for (int k = 0; k < 4; ++k) {
                const int c = q * 4 + k;
                sum_l1m += fmaxf(log1pf(-p[k]), -100.f);
                if (c == label) p_lab = p[k];
            }
        }
        const float lp_lab  = fmaxf(logf(p_lab),    -100.f);
        const float l1m_lab = fmaxf(log1pf(-p_lab), -100.f);
        cls_acc = -(sum_l1m - l1m_lab + lp_lab) * (1.f / 20.f);

        // ---- box decode + IoU ----
        const float px = ((float)gx + pb.x) * stride_f;
        const float py = ((float)gy + pb.y) * stride_f;
        const float pw = pb.z * 640.f, ph = pb.w * 640.f;
        const float bx1 = px - pw * 0.5f, by1 = py - ph * 0.5f;
        const float bx2 = px + pw * 0.5f, by2 = py + ph * 0.5f;

        const float ix1 = fmaxf(bx1, x1), iy1 = fmaxf(by1, y1);
        const float ix2 = fminf(bx2, x2), iy2 = fminf(by2, y2);
        const float inter = fmaxf(ix2 - ix1, 0.f) * fmaxf(iy2 - iy1, 0.f);
        const float a1 = (bx2 - bx1) * (by2 - by1);
        const float a2 = (x2 - x1) * (y2 - y1);
        const float iou = inter / (a1 + a2 - inter + 1e-6f);

        box_acc = 1.f - iou;
    }

    // ---- wave (64) shuffle reduction ----
#pragma unroll
    for (int off = 32; off > 0; off >>= 1) {
        box_acc += __shfl_down(box_acc, off);
        cls_acc += __shfl_down(cls_acc, off);
    }

    // ---- cross-wave (4 waves) then cross-block via device-scope atomics ----
    __shared__ float sbox[BLK / 64], scls[BLK / 64];
    const int wid = threadIdx.x >> 6, lane = threadIdx.x & 63;
    if (lane == 0) { sbox[wid] = box_acc; scls[wid] = cls_acc; }
    __syncthreads();

    if (threadIdx.x == 0) {
        float b2 = 0.f, c2 = 0.f;
#pragma unroll
        for (int w = 0; w < BLK / 64; ++w) { b2 += sbox[w]; c2 += scls[w]; }

        atomicAdd(&ws[0], b2);                  // device-scope by default on global
        atomicAdd(&ws[1], c2);
        __threadfence();                        // adds visible before ticket bump
        const unsigned old = atomicAdd((unsigned*)&ws[2], 1u);
        if (old == NBLOCKS - 1) {
            // Last block: all 25 partial pairs are in. Atomic reads (add 0) see
            // the L2-coherent accumulated values regardless of XCD.
            const float bsum = atomicAdd(&ws[0], 0.f);
            const float csum = atomicAdd(&ws[1], 0.f);
            const float box_loss = bsum * (1.f / (float)NUM_GT);
            const float cls_loss = csum * (1.f / (float)NUM_GT);
            out[0] = 7.5f * box_loss + 0.5f * cls_loss;
            out[1] = box_loss;
            out[2] = cls_loss;
            out[3] = 0.f;
        }
    }
}

extern "C" void kernel_launch(void* const* d_in, const int* in_sizes, int n_in,
                              void* d_out, int out_size, void* d_ws, size_t ws_size,
                              hipStream_t stream)
{
    const float*  cls0 = (const float*)d_in[0];
    const float*  box0 = (const float*)d_in[1];
    const float*  cls1 = (const float*)d_in[2];
    const float*  box1 = (const float*)d_in[3];
    const float*  cls2 = (const float*)d_in[4];
    const float*  box2 = (const float*)d_in[5];
    const float4* gtb  = (const float4*)d_in[6];
    const int*    gtl  = (const int*)d_in[7];
    float* ws  = (float*)d_ws;
    float* out = (float*)d_out;

    // Zero the 16-byte accumulator block (box, cls, ticket, pad).
    // hipMemsetAsync is stream-ordered and graph-capture-safe (harness reset uses it).
    hipMemsetAsync(ws, 0, 16, stream);
    yolo_wide<<<NBLOCKS, BLK, 0, stream>>>(cls0, box0, cls1, box1, cls2, box2,
                                           gtb, gtl, ws, out);
}